// Round 2
// baseline (2182.906 us; speedup 1.0000x reference)
//
#include <hip/hip_runtime.h>
#include <hip/hip_bf16.h>
#include <stdint.h>

#define FEATS   512
#define HIDDEN  64
#define CLASSES 16
#define EMB_DIM 7
#define ADJ_H   11
#define DEPTH   10

typedef __hip_bfloat16 bf16;

__device__ __forceinline__ float b2f(bf16 v) { return __bfloat162float(v); }
__device__ __forceinline__ float lo_bf(unsigned u) { return __uint_as_float(u << 16); }
__device__ __forceinline__ float hi_bf(unsigned u) { return __uint_as_float(u & 0xffff0000u); }

// ---------------- dtype detect: 1 = bf16, 0 = f32 ----------------
// Reads first 4096 halfwords of x. If data is f32, even halfwords are f32
// mantissa bits (~uniform) -> bf16 exponent field >= 134 about 47% of the
// time. If data is true bf16 ~N(0,1), essentially never.
__global__ void k_detect(const unsigned short* __restrict__ xs, int* __restrict__ flag) {
    __shared__ int cnt;
    if (threadIdx.x == 0) cnt = 0;
    __syncthreads();
    int c = 0;
    for (int i = threadIdx.x; i < 4096; i += 256) {
        unsigned e = (xs[i] >> 7) & 0xFFu;   // bf16 exponent field
        if (e >= 134u) c++;                  // |v| >= 128
    }
    atomicAdd(&cnt, c);
    __syncthreads();
    if (threadIdx.x == 0) *flag = (cnt < 64) ? 1 : 0;
}

// ---------------- generic convert (bf16 or f32 -> f32) ----------------
__global__ __launch_bounds__(256) void k_cvt(const void* __restrict__ src,
                                             float* __restrict__ dst, int cnt,
                                             const int* __restrict__ flag) {
    int i = blockIdx.x * 256 + threadIdx.x;
    if (i >= cnt) return;
    if (*flag) dst[i] = b2f(((const bf16*)src)[i]);
    else       dst[i] = ((const float*)src)[i];
}

// ---------------- degree (atomic histogram over dst) ----------------
__global__ __launch_bounds__(256) void k_deg(const int* __restrict__ edges,
                                             int* __restrict__ deg, int E) {
    int e = blockIdx.x * 256 + threadIdx.x;
    if (e < E) atomicAdd(&deg[edges[E + e]], 1);
}

// ---------------- dinv = deg>0 ? rsqrt(deg) : 0 ----------------
__global__ __launch_bounds__(256) void k_dinv(const int* __restrict__ deg,
                                              float* __restrict__ dinv, int n) {
    int i = blockIdx.x * 256 + threadIdx.x;
    if (i < n) {
        int d = deg[i];
        dinv[i] = (d > 0) ? rsqrtf((float)d) : 0.0f;
    }
}

// ---------------- exclusive scan of deg -> offs (3-kernel) ----------------
__global__ __launch_bounds__(256) void k_scan1(const int* __restrict__ deg,
                                               int* __restrict__ offs,
                                               int* __restrict__ bsum, int n) {
    __shared__ int ts[256];
    int t = threadIdx.x;
    int base = blockIdx.x * 1024 + t * 4;
    int v0 = (base + 0 < n) ? deg[base + 0] : 0;
    int v1 = (base + 1 < n) ? deg[base + 1] : 0;
    int v2 = (base + 2 < n) ? deg[base + 2] : 0;
    int v3 = (base + 3 < n) ? deg[base + 3] : 0;
    int tsum = v0 + v1 + v2 + v3;
    ts[t] = tsum;
    __syncthreads();
    for (int d = 1; d < 256; d <<= 1) {
        int add = (t >= d) ? ts[t - d] : 0;
        __syncthreads();
        ts[t] += add;
        __syncthreads();
    }
    int excl = ts[t] - tsum;
    if (base + 0 < n) offs[base + 0] = excl;
    if (base + 1 < n) offs[base + 1] = excl + v0;
    if (base + 2 < n) offs[base + 2] = excl + v0 + v1;
    if (base + 3 < n) offs[base + 3] = excl + v0 + v1 + v2;
    if (t == 255) bsum[blockIdx.x] = ts[255];
}

__global__ void k_scan2(const int* __restrict__ bsum, int* __restrict__ bpref,
                        int* __restrict__ offs, int nb, int n) {
    if (threadIdx.x == 0 && blockIdx.x == 0) {
        int run = 0;
        for (int i = 0; i < nb; ++i) { bpref[i] = run; run += bsum[i]; }
        offs[n] = run;   // == E
    }
}

__global__ __launch_bounds__(256) void k_scan3(int* __restrict__ offs,
                                               const int* __restrict__ bpref, int n) {
    int i = blockIdx.x * 256 + threadIdx.x;
    if (i < n) offs[i] += bpref[i >> 10];
}

// ---------------- CSR fill: pack (src, wnorm) per edge ----------------
__global__ __launch_bounds__(256) void k_fill(const int* __restrict__ edges,
                                              const int* __restrict__ offs,
                                              int* __restrict__ cursor,
                                              const float* __restrict__ dinv,
                                              int2* __restrict__ ew, int E) {
    int e = blockIdx.x * 256 + threadIdx.x;
    if (e < E) {
        int src = edges[e];
        int dst = edges[E + e];
        int pos = offs[dst] + atomicAdd(&cursor[dst], 1);
        float w = dinv[src] * dinv[dst];
        ew[pos] = make_int2(src, __float_as_int(w));
    }
}

// ---------------- MLP constants (f32 inputs, emb row folded into bias) ----------------
__global__ void k_mlpconst(const float* __restrict__ emb, const float* __restrict__ W_a1,
                           const float* __restrict__ b_a1, const float* __restrict__ W_a2,
                           const float* __restrict__ b_a2, float* __restrict__ C) {
    int j = threadIdx.x;
    if (j < ADJ_H) {
        float c = b_a1[j];
        for (int k = 0; k < EMB_DIM; ++k)
            c += emb[k] * W_a1[(2 + k) * ADJ_H + j];
        C[j]      = c;                     // bias (incl emb contribution)
        C[11 + j] = W_a1[0 * ADJ_H + j];   // weight on h
        C[22 + j] = W_a1[1 * ADJ_H + j];   // weight on h0
        C[33 + j] = W_a2[j];               // output weight
    }
    if (j == 0) C[44] = b_a2[0];
}

// ---------------- GEMM: h = x @ W_dim + b_dim  (f32 out) ----------------
__global__ __launch_bounds__(256) void k_gemm(const void* __restrict__ xraw,
                                              const int* __restrict__ flag,
                                              const float* __restrict__ Wf,
                                              const float* __restrict__ bdf,
                                              float* __restrict__ out, int n) {
    __shared__ float xs[16][FEATS + 4];   // +4 pad breaks bank conflicts
    int t = threadIdx.x;
    int rowbase = blockIdx.x * 16;
    if (*flag) {
        for (int it = 0; it < 4; ++it) {
            int e = it * 256 + t;           // 1024 chunks: 16 rows x 64 chunks of 8
            int r = e >> 6;
            int kc = (e & 63) * 8;
            int grow = rowbase + r;
            uint4 v = make_uint4(0u, 0u, 0u, 0u);
            if (grow < n)
                v = *(const uint4*)((const unsigned short*)xraw + (size_t)grow * FEATS + kc);
            float* dst = &xs[r][kc];
            dst[0] = lo_bf(v.x); dst[1] = hi_bf(v.x);
            dst[2] = lo_bf(v.y); dst[3] = hi_bf(v.y);
            dst[4] = lo_bf(v.z); dst[5] = hi_bf(v.z);
            dst[6] = lo_bf(v.w); dst[7] = hi_bf(v.w);
        }
    } else {
        for (int it = 0; it < 8; ++it) {
            int e = it * 256 + t;           // 2048 chunks: 16 rows x 128 chunks of 4
            int r = e >> 7;
            int kc = (e & 127) * 4;
            int grow = rowbase + r;
            float4 v = make_float4(0.f, 0.f, 0.f, 0.f);
            if (grow < n)
                v = *(const float4*)((const float*)xraw + (size_t)grow * FEATS + kc);
            float* dst = &xs[r][kc];
            dst[0] = v.x; dst[1] = v.y; dst[2] = v.z; dst[3] = v.w;
        }
    }
    __syncthreads();
    int r = t >> 4;
    int cg = (t & 15) * 4;
    float4 acc;
    acc.x = bdf[cg + 0]; acc.y = bdf[cg + 1];
    acc.z = bdf[cg + 2]; acc.w = bdf[cg + 3];
    const float* xr = xs[r];
    #pragma unroll 8
    for (int k = 0; k < FEATS; ++k) {
        float xv = xr[k];
        float4 wv = *(const float4*)(Wf + k * HIDDEN + cg);
        acc.x += xv * wv.x; acc.y += xv * wv.y;
        acc.z += xv * wv.z; acc.w += xv * wv.w;
    }
    int grow = rowbase + r;
    if (grow < n)
        *(float4*)(out + (size_t)grow * HIDDEN + cg) = acc;
}

// ---------------- conv: hout = 0.9*A@hin + 0.1*h0 ; one wave per node ----------------
__global__ __launch_bounds__(256) void k_conv(const int* __restrict__ offs,
                                              const int2* __restrict__ ew,
                                              const float* __restrict__ hin,
                                              const float* __restrict__ h0,
                                              float* __restrict__ hout, int n) {
    int wid = (blockIdx.x * 256 + threadIdx.x) >> 6;
    if (wid >= n) return;
    int lane = threadIdx.x & 63;
    int grp = lane >> 4;          // 4 edge subgroups per wave
    int ch = (lane & 15) * 4;     // 16 lanes x float4 = 64 channels
    int start = offs[wid], end = offs[wid + 1];
    float4 acc = make_float4(0.f, 0.f, 0.f, 0.f);
    for (int p = start + grp; p < end; p += 4) {
        int2 cw = ew[p];
        float wgt = __int_as_float(cw.y);
        float4 hv = *(const float4*)(hin + (size_t)cw.x * HIDDEN + ch);
        acc.x += wgt * hv.x; acc.y += wgt * hv.y;
        acc.z += wgt * hv.z; acc.w += wgt * hv.w;
    }
    // reduce the 4 edge subgroups (lanes l, l^16, l^32, l^48)
    acc.x += __shfl_xor(acc.x, 16); acc.y += __shfl_xor(acc.y, 16);
    acc.z += __shfl_xor(acc.z, 16); acc.w += __shfl_xor(acc.w, 16);
    acc.x += __shfl_xor(acc.x, 32); acc.y += __shfl_xor(acc.y, 32);
    acc.z += __shfl_xor(acc.z, 32); acc.w += __shfl_xor(acc.w, 32);
    if (grp == 0) {
        size_t o = (size_t)wid * HIDDEN + ch;
        float4 h0v = *(const float4*)(h0 + o);
        float4 r;
        r.x = 0.9f * acc.x + 0.1f * h0v.x;
        r.y = 0.9f * acc.y + 0.1f * h0v.y;
        r.z = 0.9f * acc.z + 0.1f * h0v.z;
        r.w = 0.9f * acc.w + 0.1f * h0v.w;
        *(float4*)(hout + o) = r;
    }
}

// ---------------- elementwise edge-MLP (in-place on h0 buffer) ----------------
__global__ __launch_bounds__(256) void k_mlp(float* __restrict__ h0io,
                                             const float* __restrict__ hc,
                                             const float* __restrict__ C, int total) {
    int i = blockIdx.x * 256 + threadIdx.x;
    if (i >= total) return;
    float hv = hc[i];
    float h0v = h0io[i];
    float s = C[44];
    #pragma unroll
    for (int j = 0; j < ADJ_H; ++j) {
        float z = C[j] + hv * C[11 + j] + h0v * C[22 + j];
        z = (z > 0.f) ? z : 0.01f * z;     // leaky_relu 0.01
        s += z * C[33 + j];
    }
    h0io[i] = 0.5f * s;
}

// ---------------- classifier: out = h @ W_cls + b_cls ----------------
__global__ __launch_bounds__(256) void k_cls(const float* __restrict__ h,
                                             const float* __restrict__ Wc,
                                             const float* __restrict__ bc,
                                             void* __restrict__ outraw,
                                             const int* __restrict__ flag, int n) {
    __shared__ float hs[64][65];
    __shared__ float ws[64 * 16];
    __shared__ float bs[16];
    int t = threadIdx.x;
    int base = blockIdx.x * 64;
    for (int it = 0; it < 16; ++it) {
        int e = it * 256 + t;
        int rr = e >> 6, cc = e & 63;
        int g = base + rr;
        hs[rr][cc] = (g < n) ? h[(size_t)g * HIDDEN + cc] : 0.f;
    }
    for (int it = 0; it < 4; ++it) {
        int e = it * 256 + t;
        ws[e] = Wc[e];
    }
    if (t < 16) bs[t] = bc[t];
    __syncthreads();
    int isbf = *flag;
    for (int q = 0; q < 4; ++q) {
        int e = q * 256 + t;        // 1024 (node,cls) pairs
        int node = e >> 4, cls = e & 15;
        float acc = bs[cls];
        #pragma unroll 8
        for (int k = 0; k < HIDDEN; ++k)
            acc += hs[node][k] * ws[k * 16 + cls];
        int g = base + node;
        if (g < n) {
            size_t oi = (size_t)g * CLASSES + cls;
            if (isbf) ((bf16*)outraw)[oi] = __float2bfloat16(acc);
            else      ((float*)outraw)[oi] = acc;
        }
    }
}

extern "C" void kernel_launch(void* const* d_in, const int* in_sizes, int n_in,
                              void* d_out, int out_size, void* d_ws, size_t ws_size,
                              hipStream_t stream) {
    const void* x     = d_in[0];
    const int*  edges = (const int*)d_in[1];
    const void* W_dim = d_in[2];
    const void* b_dim = d_in[3];
    const void* emb   = d_in[4];
    const void* W_a1  = d_in[5];
    const void* b_a1  = d_in[6];
    const void* W_a2  = d_in[7];
    const void* b_a2  = d_in[8];
    const void* Wcls  = d_in[9];
    const void* bcls  = d_in[10];

    const int n = in_sizes[0] / FEATS;     // 100000
    const int E = in_sizes[1] / 2;         // 1600000

    char* w = (char*)d_ws;
    size_t off = 0;
    auto alloc = [&](size_t bytes) -> void* {
        void* p = w + off;
        off = (off + bytes + 255) & ~(size_t)255;
        return p;
    };
    int*   deg    = (int*)  alloc((size_t)n * 4);
    int*   cursor = (int*)  alloc((size_t)n * 4);
    int*   offs   = (int*)  alloc((size_t)(n + 1) * 4);
    float* dinv   = (float*)alloc((size_t)n * 4);
    int*   bsum   = (int*)  alloc(4096 * 4);
    int*   bpref  = (int*)  alloc(4096 * 4);
    int2*  ew     = (int2*) alloc((size_t)E * 8);
    float* Wf     = (float*)alloc((size_t)FEATS * HIDDEN * 4);
    float* consts = (float*)alloc(64 * 4);
    int*   flag   = (int*)  alloc(256);
    float* bdf    = (float*)alloc(HIDDEN * 4);
    float* embf   = (float*)alloc(EMB_DIM * 4);
    float* wa1f   = (float*)alloc((2 + EMB_DIM) * ADJ_H * 4);
    float* ba1f   = (float*)alloc(ADJ_H * 4);
    float* wa2f   = (float*)alloc(ADJ_H * 4);
    float* ba2f   = (float*)alloc(4);
    float* wcf    = (float*)alloc(HIDDEN * CLASSES * 4);
    float* bcf    = (float*)alloc(CLASSES * 4);
    float* buf0   = (float*)alloc((size_t)n * HIDDEN * 4);
    float* bufA   = (float*)alloc((size_t)n * HIDDEN * 4);
    float* bufB   = (float*)alloc((size_t)n * HIDDEN * 4);

    int gE = (E + 255) / 256;
    int gN = (n + 255) / 256;
    int nb = (n + 1023) / 1024;
    int gConv = (n + 3) / 4;    // 4 waves per block, 1 wave per node

    // zero deg + cursor (contiguous at start of ws)
    hipMemsetAsync(deg, 0, ((char*)cursor - (char*)deg) + (size_t)n * 4, stream);

    k_detect<<<1, 256, 0, stream>>>((const unsigned short*)x, flag);

    k_deg  <<<gE, 256, 0, stream>>>(edges, deg, E);
    k_dinv <<<gN, 256, 0, stream>>>(deg, dinv, n);
    k_scan1<<<nb, 256, 0, stream>>>(deg, offs, bsum, n);
    k_scan2<<<1, 64, 0, stream>>>(bsum, bpref, offs, nb, n);
    k_scan3<<<gN, 256, 0, stream>>>(offs, bpref, n);
    k_fill <<<gE, 256, 0, stream>>>(edges, offs, cursor, dinv, ew, E);

    k_cvt<<<(FEATS * HIDDEN + 255) / 256, 256, 0, stream>>>(W_dim, Wf, FEATS * HIDDEN, flag);
    k_cvt<<<1, 256, 0, stream>>>(b_dim, bdf, HIDDEN, flag);
    k_cvt<<<1, 256, 0, stream>>>(emb, embf, EMB_DIM, flag);          // only emb[0] row needed
    k_cvt<<<1, 256, 0, stream>>>(W_a1, wa1f, (2 + EMB_DIM) * ADJ_H, flag);
    k_cvt<<<1, 256, 0, stream>>>(b_a1, ba1f, ADJ_H, flag);
    k_cvt<<<1, 256, 0, stream>>>(W_a2, wa2f, ADJ_H, flag);
    k_cvt<<<1, 256, 0, stream>>>(b_a2, ba2f, 1, flag);
    k_cvt<<<(HIDDEN * CLASSES + 255) / 256, 256, 0, stream>>>(Wcls, wcf, HIDDEN * CLASSES, flag);
    k_cvt<<<1, 256, 0, stream>>>(bcls, bcf, CLASSES, flag);

    k_mlpconst<<<1, 64, 0, stream>>>(embf, wa1f, ba1f, wa2f, ba2f, consts);

    k_gemm<<<(n + 15) / 16, 256, 0, stream>>>(x, flag, Wf, bdf, buf0, n);

    const float* hin = buf0;
    for (int i = 0; i < DEPTH; ++i) {
        float* ho = (i & 1) ? bufB : bufA;
        k_conv<<<gConv, 256, 0, stream>>>(offs, ew, hin, buf0, ho, n);
        hin = ho;
    }
    // hin == bufB after 10 iters
    k_mlp<<<((size_t)n * HIDDEN + 255) / 256, 256, 0, stream>>>(buf0, hin, consts, n * HIDDEN);

    hin = buf0;
    for (int i = 0; i < DEPTH; ++i) {
        float* ho = (i & 1) ? bufB : bufA;
        k_conv<<<gConv, 256, 0, stream>>>(offs, ew, hin, buf0, ho, n);
        hin = ho;
    }
    k_cls<<<(n + 63) / 64, 256, 0, stream>>>(hin, wcf, bcf, d_out, flag, n);
}

// Round 3
// 1490.489 us; speedup vs baseline: 1.4646x; 1.4646x over previous
//
#include <hip/hip_runtime.h>
#include <hip/hip_bf16.h>
#include <hip/hip_fp16.h>
#include <stdint.h>

#define FEATS   512
#define HIDDEN  64
#define CLASSES 16
#define EMB_DIM 7
#define ADJ_H   11
#define DEPTH   10

typedef __hip_bfloat16 bf16;
typedef __attribute__((ext_vector_type(8))) short short8;
typedef __attribute__((ext_vector_type(4))) float f32x4;

__device__ __forceinline__ float b2f(bf16 v) { return __bfloat162float(v); }

__device__ __forceinline__ float4 ld_half4(const __half* p) {
    uint2 rv = *(const uint2*)p;
    __half2 a = *(__half2*)&rv.x;
    __half2 b = *(__half2*)&rv.y;
    float2 fa = __half22float2(a);
    float2 fb = __half22float2(b);
    return make_float4(fa.x, fa.y, fb.x, fb.y);
}
__device__ __forceinline__ void st_half4(__half* p, float4 v) {
    __half2 a = __floats2half2_rn(v.x, v.y);
    __half2 b = __floats2half2_rn(v.z, v.w);
    uint2 rv;
    rv.x = *(unsigned*)&a;
    rv.y = *(unsigned*)&b;
    *(uint2*)p = rv;
}

// ---------------- dtype detect: 1 = bf16, 0 = f32 ----------------
__global__ void k_detect(const unsigned short* __restrict__ xs, int* __restrict__ flag) {
    __shared__ int cnt;
    if (threadIdx.x == 0) cnt = 0;
    __syncthreads();
    int c = 0;
    for (int i = threadIdx.x; i < 4096; i += 256) {
        unsigned e = (xs[i] >> 7) & 0xFFu;
        if (e >= 134u) c++;
    }
    atomicAdd(&cnt, c);
    __syncthreads();
    if (threadIdx.x == 0) *flag = (cnt < 64) ? 1 : 0;
}

// ---------------- generic convert (bf16 or f32 -> f32) ----------------
__global__ __launch_bounds__(256) void k_cvt(const void* __restrict__ src,
                                             float* __restrict__ dst, int cnt,
                                             const int* __restrict__ flag) {
    int i = blockIdx.x * 256 + threadIdx.x;
    if (i >= cnt) return;
    if (*flag) dst[i] = b2f(((const bf16*)src)[i]);
    else       dst[i] = ((const float*)src)[i];
}

// ---------------- degree ----------------
__global__ __launch_bounds__(256) void k_deg(const int* __restrict__ edges,
                                             int* __restrict__ deg, int E) {
    int e = blockIdx.x * 256 + threadIdx.x;
    if (e < E) atomicAdd(&deg[edges[E + e]], 1);
}

__global__ __launch_bounds__(256) void k_dinv(const int* __restrict__ deg,
                                              float* __restrict__ dinv, int n) {
    int i = blockIdx.x * 256 + threadIdx.x;
    if (i < n) {
        int d = deg[i];
        dinv[i] = (d > 0) ? rsqrtf((float)d) : 0.0f;
    }
}

// ---------------- exclusive scan ----------------
__global__ __launch_bounds__(256) void k_scan1(const int* __restrict__ deg,
                                               int* __restrict__ offs,
                                               int* __restrict__ bsum, int n) {
    __shared__ int ts[256];
    int t = threadIdx.x;
    int base = blockIdx.x * 1024 + t * 4;
    int v0 = (base + 0 < n) ? deg[base + 0] : 0;
    int v1 = (base + 1 < n) ? deg[base + 1] : 0;
    int v2 = (base + 2 < n) ? deg[base + 2] : 0;
    int v3 = (base + 3 < n) ? deg[base + 3] : 0;
    int tsum = v0 + v1 + v2 + v3;
    ts[t] = tsum;
    __syncthreads();
    for (int d = 1; d < 256; d <<= 1) {
        int add = (t >= d) ? ts[t - d] : 0;
        __syncthreads();
        ts[t] += add;
        __syncthreads();
    }
    int excl = ts[t] - tsum;
    if (base + 0 < n) offs[base + 0] = excl;
    if (base + 1 < n) offs[base + 1] = excl + v0;
    if (base + 2 < n) offs[base + 2] = excl + v0 + v1;
    if (base + 3 < n) offs[base + 3] = excl + v0 + v1 + v2;
    if (t == 255) bsum[blockIdx.x] = ts[255];
}

__global__ void k_scan2(const int* __restrict__ bsum, int* __restrict__ bpref,
                        int* __restrict__ offs, int nb, int n) {
    if (threadIdx.x == 0 && blockIdx.x == 0) {
        int run = 0;
        for (int i = 0; i < nb; ++i) { bpref[i] = run; run += bsum[i]; }
        offs[n] = run;
    }
}

__global__ __launch_bounds__(256) void k_scan3(int* __restrict__ offs,
                                               const int* __restrict__ bpref, int n) {
    int i = blockIdx.x * 256 + threadIdx.x;
    if (i < n) offs[i] += bpref[i >> 10];
}

// ---------------- CSR fill ----------------
__global__ __launch_bounds__(256) void k_fill(const int* __restrict__ edges,
                                              const int* __restrict__ offs,
                                              int* __restrict__ cursor,
                                              const float* __restrict__ dinv,
                                              int2* __restrict__ ew, int E) {
    int e = blockIdx.x * 256 + threadIdx.x;
    if (e < E) {
        int src = edges[e];
        int dst = edges[E + e];
        int pos = offs[dst] + atomicAdd(&cursor[dst], 1);
        float w = dinv[src] * dinv[dst];
        ew[pos] = make_int2(src, __float_as_int(w));
    }
}

// ---------------- MLP constants ----------------
__global__ void k_mlpconst(const float* __restrict__ emb, const float* __restrict__ W_a1,
                           const float* __restrict__ b_a1, const float* __restrict__ W_a2,
                           const float* __restrict__ b_a2, float* __restrict__ C) {
    int j = threadIdx.x;
    if (j < ADJ_H) {
        float c = b_a1[j];
        for (int k = 0; k < EMB_DIM; ++k)
            c += emb[k] * W_a1[(2 + k) * ADJ_H + j];
        C[j]      = c;
        C[11 + j] = W_a1[0 * ADJ_H + j];
        C[22 + j] = W_a1[1 * ADJ_H + j];
        C[33 + j] = W_a2[j];
    }
    if (j == 0) C[44] = b_a2[0];
}

// ---------------- MFMA GEMM: h = x @ W + b -> fp16 out ----------------
// Block: 256 thr = 4 waves; wave handles 64 rows x 64 cols; block = 256 rows.
// W^T staged in LDS as bf16 [64][520] (pad 8 shorts keeps 16B align, spreads banks).
__global__ __launch_bounds__(256) void k_gemm_mfma(const void* __restrict__ xraw,
                                                   const int* __restrict__ flag,
                                                   const float* __restrict__ Wf,
                                                   const float* __restrict__ bdf,
                                                   __half* __restrict__ out, int n) {
    __shared__ short Wt[64 * 520];
    int t = threadIdx.x;
    // stage W^T (Wf is f32 [512][64]; truncation to bf16 is lossless for bf16-origin data)
    for (int e = t; e < FEATS * HIDDEN; e += 256) {
        int k = e >> 6, nn = e & 63;
        Wt[nn * 520 + k] = (short)(__float_as_uint(Wf[e]) >> 16);
    }
    __syncthreads();

    int wv = t >> 6;
    int lane = t & 63;
    int quad = lane >> 4, l16 = lane & 15;
    int rowbase = blockIdx.x * 256 + wv * 64;

    f32x4 acc[4][4];   // [row-tile][n-tile]
    #pragma unroll
    for (int a = 0; a < 4; ++a)
        #pragma unroll
        for (int b = 0; b < 4; ++b)
            acc[a][b] = (f32x4){0.f, 0.f, 0.f, 0.f};

    int isbf = *flag;
    if (isbf) {
        const short* x = (const short*)xraw;
        for (int ks = 0; ks < 16; ++ks) {
            short8 bfr[4];
            #pragma unroll
            for (int nt = 0; nt < 4; ++nt)
                bfr[nt] = *(const short8*)&Wt[(nt * 16 + l16) * 520 + ks * 32 + quad * 8];
            #pragma unroll
            for (int rt = 0; rt < 4; ++rt) {
                int arow = rowbase + rt * 16 + l16;
                if (arow >= n) arow = n - 1;            // clamp; garbage rows never stored
                short8 a = *(const short8*)(x + (size_t)arow * FEATS + ks * 32 + quad * 8);
                #pragma unroll
                for (int nt = 0; nt < 4; ++nt)
                    acc[rt][nt] = __builtin_amdgcn_mfma_f32_16x16x32_bf16(a, bfr[nt], acc[rt][nt], 0, 0, 0);
            }
        }
    } else {
        const float* x = (const float*)xraw;
        for (int ks = 0; ks < 16; ++ks) {
            short8 bfr[4];
            #pragma unroll
            for (int nt = 0; nt < 4; ++nt)
                bfr[nt] = *(const short8*)&Wt[(nt * 16 + l16) * 520 + ks * 32 + quad * 8];
            #pragma unroll
            for (int rt = 0; rt < 4; ++rt) {
                int arow = rowbase + rt * 16 + l16;
                if (arow >= n) arow = n - 1;
                const float* ap = x + (size_t)arow * FEATS + ks * 32 + quad * 8;
                short8 a;
                #pragma unroll
                for (int j = 0; j < 8; ++j)
                    a[j] = (short)(__float_as_uint(ap[j]) >> 16);
                #pragma unroll
                for (int nt = 0; nt < 4; ++nt)
                    acc[rt][nt] = __builtin_amdgcn_mfma_f32_16x16x32_bf16(a, bfr[nt], acc[rt][nt], 0, 0, 0);
            }
        }
    }

    float bias[4];
    #pragma unroll
    for (int nt = 0; nt < 4; ++nt) bias[nt] = bdf[nt * 16 + l16];

    #pragma unroll
    for (int rt = 0; rt < 4; ++rt)
        #pragma unroll
        for (int nt = 0; nt < 4; ++nt) {
            int col = nt * 16 + l16;
            #pragma unroll
            for (int r = 0; r < 4; ++r) {
                int grow = rowbase + rt * 16 + quad * 4 + r;
                if (grow < n)
                    out[(size_t)grow * HIDDEN + col] = __float2half(acc[rt][nt][r] + bias[nt]);
            }
        }
}

// ---------------- conv: hout = 0.9*A@hin + 0.1*h0 ; one wave per node, fp16 h ----------------
__global__ __launch_bounds__(256) void k_conv(const int* __restrict__ offs,
                                              const int2* __restrict__ ew,
                                              const __half* __restrict__ hin,
                                              const __half* __restrict__ h0,
                                              __half* __restrict__ hout, int n) {
    int wid = (blockIdx.x * 256 + threadIdx.x) >> 6;
    if (wid >= n) return;
    int lane = threadIdx.x & 63;
    int grp = lane >> 4;
    int ch = (lane & 15) * 4;
    int start = offs[wid], end = offs[wid + 1];
    float4 a0 = make_float4(0.f, 0.f, 0.f, 0.f);
    float4 a1 = make_float4(0.f, 0.f, 0.f, 0.f);
    int p = start + grp;
    // 2 independent gather chains per group
    for (; p + 4 < end; p += 8) {
        int2 e0 = ew[p];
        int2 e1 = ew[p + 4];
        float w0 = __int_as_float(e0.y);
        float w1 = __int_as_float(e1.y);
        float4 v0 = ld_half4(hin + (size_t)e0.x * HIDDEN + ch);
        float4 v1 = ld_half4(hin + (size_t)e1.x * HIDDEN + ch);
        a0.x += w0 * v0.x; a0.y += w0 * v0.y; a0.z += w0 * v0.z; a0.w += w0 * v0.w;
        a1.x += w1 * v1.x; a1.y += w1 * v1.y; a1.z += w1 * v1.z; a1.w += w1 * v1.w;
    }
    if (p < end) {
        int2 e0 = ew[p];
        float w0 = __int_as_float(e0.y);
        float4 v0 = ld_half4(hin + (size_t)e0.x * HIDDEN + ch);
        a0.x += w0 * v0.x; a0.y += w0 * v0.y; a0.z += w0 * v0.z; a0.w += w0 * v0.w;
    }
    float4 acc = make_float4(a0.x + a1.x, a0.y + a1.y, a0.z + a1.z, a0.w + a1.w);
    acc.x += __shfl_xor(acc.x, 16); acc.y += __shfl_xor(acc.y, 16);
    acc.z += __shfl_xor(acc.z, 16); acc.w += __shfl_xor(acc.w, 16);
    acc.x += __shfl_xor(acc.x, 32); acc.y += __shfl_xor(acc.y, 32);
    acc.z += __shfl_xor(acc.z, 32); acc.w += __shfl_xor(acc.w, 32);
    if (grp == 0) {
        size_t o = (size_t)wid * HIDDEN + ch;
        float4 h0v = ld_half4(h0 + o);
        float4 r;
        r.x = 0.9f * acc.x + 0.1f * h0v.x;
        r.y = 0.9f * acc.y + 0.1f * h0v.y;
        r.z = 0.9f * acc.z + 0.1f * h0v.z;
        r.w = 0.9f * acc.w + 0.1f * h0v.w;
        st_half4(hout + o, r);
    }
}

// ---------------- elementwise edge-MLP (half2-vectorized, in-place on h0) ----------------
__global__ __launch_bounds__(256) void k_mlp(__half* __restrict__ h0io,
                                             const __half* __restrict__ hc,
                                             const float* __restrict__ C, int total2) {
    int i = blockIdx.x * 256 + threadIdx.x;
    if (i >= total2) return;
    float2 hv  = __half22float2(((const __half2*)hc)[i]);
    float2 h0v = __half22float2(((const __half2*)h0io)[i]);
    float sx = C[44], sy = C[44];
    #pragma unroll
    for (int j = 0; j < ADJ_H; ++j) {
        float bj = C[j], wh = C[11 + j], w0 = C[22 + j], wo = C[33 + j];
        float zx = bj + hv.x * wh + h0v.x * w0;
        float zy = bj + hv.y * wh + h0v.y * w0;
        zx = (zx > 0.f) ? zx : 0.01f * zx;
        zy = (zy > 0.f) ? zy : 0.01f * zy;
        sx += zx * wo;
        sy += zy * wo;
    }
    ((__half2*)h0io)[i] = __floats2half2_rn(0.5f * sx, 0.5f * sy);
}

// ---------------- classifier ----------------
__global__ __launch_bounds__(256) void k_cls(const __half* __restrict__ h,
                                             const float* __restrict__ Wc,
                                             const float* __restrict__ bc,
                                             void* __restrict__ outraw,
                                             const int* __restrict__ flag, int n) {
    __shared__ float hs[64][65];
    __shared__ float ws[64 * 16];
    __shared__ float bs[16];
    int t = threadIdx.x;
    int base = blockIdx.x * 64;
    for (int it = 0; it < 16; ++it) {
        int e = it * 256 + t;
        int rr = e >> 6, cc = e & 63;
        int g = base + rr;
        hs[rr][cc] = (g < n) ? __half2float(h[(size_t)g * HIDDEN + cc]) : 0.f;
    }
    for (int it = 0; it < 4; ++it) {
        int e = it * 256 + t;
        ws[e] = Wc[e];
    }
    if (t < 16) bs[t] = bc[t];
    __syncthreads();
    int isbf = *flag;
    for (int q = 0; q < 4; ++q) {
        int e = q * 256 + t;
        int node = e >> 4, cls = e & 15;
        float acc = bs[cls];
        #pragma unroll 8
        for (int k = 0; k < HIDDEN; ++k)
            acc += hs[node][k] * ws[k * 16 + cls];
        int g = base + node;
        if (g < n) {
            size_t oi = (size_t)g * CLASSES + cls;
            if (isbf) ((bf16*)outraw)[oi] = __float2bfloat16(acc);
            else      ((float*)outraw)[oi] = acc;
        }
    }
}

extern "C" void kernel_launch(void* const* d_in, const int* in_sizes, int n_in,
                              void* d_out, int out_size, void* d_ws, size_t ws_size,
                              hipStream_t stream) {
    const void* x     = d_in[0];
    const int*  edges = (const int*)d_in[1];
    const void* W_dim = d_in[2];
    const void* b_dim = d_in[3];
    const void* emb   = d_in[4];
    const void* W_a1  = d_in[5];
    const void* b_a1  = d_in[6];
    const void* W_a2  = d_in[7];
    const void* b_a2  = d_in[8];
    const void* Wcls  = d_in[9];
    const void* bcls  = d_in[10];

    const int n = in_sizes[0] / FEATS;     // 100000
    const int E = in_sizes[1] / 2;         // 1600000

    char* w = (char*)d_ws;
    size_t off = 0;
    auto alloc = [&](size_t bytes) -> void* {
        void* p = w + off;
        off = (off + bytes + 255) & ~(size_t)255;
        return p;
    };
    int*   deg    = (int*)  alloc((size_t)n * 4);
    int*   cursor = (int*)  alloc((size_t)n * 4);
    int*   offs   = (int*)  alloc((size_t)(n + 1) * 4);
    float* dinv   = (float*)alloc((size_t)n * 4);
    int*   bsum   = (int*)  alloc(4096 * 4);
    int*   bpref  = (int*)  alloc(4096 * 4);
    int2*  ew     = (int2*) alloc((size_t)E * 8);
    float* Wf     = (float*)alloc((size_t)FEATS * HIDDEN * 4);
    float* consts = (float*)alloc(64 * 4);
    int*   flag   = (int*)  alloc(256);
    float* bdf    = (float*)alloc(HIDDEN * 4);
    float* embf   = (float*)alloc(EMB_DIM * 4);
    float* wa1f   = (float*)alloc((2 + EMB_DIM) * ADJ_H * 4);
    float* ba1f   = (float*)alloc(ADJ_H * 4);
    float* wa2f   = (float*)alloc(ADJ_H * 4);
    float* ba2f   = (float*)alloc(4);
    float* wcf    = (float*)alloc(HIDDEN * CLASSES * 4);
    float* bcf    = (float*)alloc(CLASSES * 4);
    __half* buf0  = (__half*)alloc((size_t)n * HIDDEN * 2);
    __half* bufA  = (__half*)alloc((size_t)n * HIDDEN * 2);
    __half* bufB  = (__half*)alloc((size_t)n * HIDDEN * 2);

    int gE = (E + 255) / 256;
    int gN = (n + 255) / 256;
    int nb = (n + 1023) / 1024;
    int gConv = (n + 3) / 4;

    hipMemsetAsync(deg, 0, ((char*)cursor - (char*)deg) + (size_t)n * 4, stream);

    k_detect<<<1, 256, 0, stream>>>((const unsigned short*)x, flag);

    k_deg  <<<gE, 256, 0, stream>>>(edges, deg, E);
    k_dinv <<<gN, 256, 0, stream>>>(deg, dinv, n);
    k_scan1<<<nb, 256, 0, stream>>>(deg, offs, bsum, n);
    k_scan2<<<1, 64, 0, stream>>>(bsum, bpref, offs, nb, n);
    k_scan3<<<gN, 256, 0, stream>>>(offs, bpref, n);
    k_fill <<<gE, 256, 0, stream>>>(edges, offs, cursor, dinv, ew, E);

    k_cvt<<<(FEATS * HIDDEN + 255) / 256, 256, 0, stream>>>(W_dim, Wf, FEATS * HIDDEN, flag);
    k_cvt<<<1, 256, 0, stream>>>(b_dim, bdf, HIDDEN, flag);
    k_cvt<<<1, 256, 0, stream>>>(emb, embf, EMB_DIM, flag);
    k_cvt<<<1, 256, 0, stream>>>(W_a1, wa1f, (2 + EMB_DIM) * ADJ_H, flag);
    k_cvt<<<1, 256, 0, stream>>>(b_a1, ba1f, ADJ_H, flag);
    k_cvt<<<1, 256, 0, stream>>>(W_a2, wa2f, ADJ_H, flag);
    k_cvt<<<1, 256, 0, stream>>>(b_a2, ba2f, 1, flag);
    k_cvt<<<(HIDDEN * CLASSES + 255) / 256, 256, 0, stream>>>(Wcls, wcf, HIDDEN * CLASSES, flag);
    k_cvt<<<1, 256, 0, stream>>>(bcls, bcf, CLASSES, flag);

    k_mlpconst<<<1, 64, 0, stream>>>(embf, wa1f, ba1f, wa2f, ba2f, consts);

    k_gemm_mfma<<<(n + 255) / 256, 256, 0, stream>>>(x, flag, Wf, bdf, buf0, n);

    const __half* hin = buf0;
    for (int i = 0; i < DEPTH; ++i) {
        __half* ho = (i & 1) ? bufB : bufA;
        k_conv<<<gConv, 256, 0, stream>>>(offs, ew, hin, buf0, ho, n);
        hin = ho;
    }
    k_mlp<<<(n * (HIDDEN / 2) + 255) / 256, 256, 0, stream>>>(buf0, hin, consts, n * (HIDDEN / 2));

    hin = buf0;
    for (int i = 0; i < DEPTH; ++i) {
        __half* ho = (i & 1) ? bufB : bufA;
        k_conv<<<gConv, 256, 0, stream>>>(offs, ew, hin, buf0, ho, n);
        hin = ho;
    }
    k_cls<<<(n + 63) / 64, 256, 0, stream>>>(hin, wcf, bcf, d_out, flag, n);
}